// Round 1
// baseline (83.617 us; speedup 1.0000x reference)
//
#include <hip/hip_runtime.h>
#include <math.h>

#define NB 50      // NB_STEPS
#define NS 52      // 51 nodes padded to 52 (index 51 has zero weight)
#define H  128     // hidden dim
#define SPT 13     // s-nodes per thread (4 threads/output * 13 = 52)

// One output point is handled by 4 consecutive threads; each covers 13
// quadrature nodes (last chunk padded with a zero-weight node). The j-loop
// (hidden units) is innermost with the 13 accumulators register-blocked so
// each LDS broadcast load of (w1,b1,w2) is amortized over 13 fma/max/fma.
__global__ __launch_bounds__(256) void umnn_kernel(
    const float* __restrict__ x,
    const float* __restrict__ W1,
    const float* __restrict__ b1,
    const float* __restrict__ W2,
    const float* __restrict__ b2,
    float* __restrict__ out,
    int N)
{
    __shared__ float s_w1[H], s_b1[H], s_w2[H];
    __shared__ float s_ccw[NS], s_ccs[NS];

    const int tid = threadIdx.x;

    if (tid < H) {
        s_w1[tid] = W1[tid];
        s_b1[tid] = b1[tid];
        s_w2[tid] = W2[tid];
    }

    // Clenshaw-Curtis weights/nodes, faithful port of the numpy construction.
    // Only threads 0..51 (wave 0) do this; ~26 cosf each.
    if (tid < NS) {
        const int s = tid;
        if (s <= NB) {
            s_ccs[s] = cosf((float)s * ((float)M_PI / (float)NB));
            float sum = 0.0f;
            for (int k = 0; k <= NB; k += 2) {
                float L;
                if (s == 0)       L = 0.5f;           // lam[:,0] = 0.5
                else if (s == NB) L = 0.5f;           // 0.5*cos(k*pi), k even
                else              L = cosf((float)(k * s) * ((float)M_PI / (float)NB));
                const float Wk = (k == 0) ? 1.0f : 2.0f / (1.0f - (float)(k * k));
                sum += L * Wk;
            }
            s_ccw[s] = sum * (2.0f / (float)NB);
        } else {
            s_ccs[s] = 0.0f;   // padded node: must be finite (zero weight kills it)
            s_ccw[s] = 0.0f;
        }
    }
    __syncthreads();

    const int g     = blockIdx.x * blockDim.x + tid;
    const int n     = g >> 2;       // output point index
    const int chunk = g & 3;        // which 13-node slice
    if (n >= N) return;

    const float xf  = x[n];
    const float b2v = b2[0];
    const int   s0  = chunk * SPT;

    float Xs[SPT], acc[SPT];
#pragma unroll
    for (int i = 0; i < SPT; ++i) {
        Xs[i]  = xf * (s_ccs[s0 + i] + 1.0f) * 0.5f;
        acc[i] = 0.0f;
    }

#pragma unroll 2
    for (int j = 0; j < H; ++j) {
        const float w1 = s_w1[j];   // wave-uniform -> LDS broadcast
        const float bb = s_b1[j];
        const float w2 = s_w2[j];
#pragma unroll
        for (int i = 0; i < SPT; ++i) {
            float h = fmaf(Xs[i], w1, bb);
            h = fmaxf(h, 0.0f);
            acc[i] = fmaf(h, w2, acc[i]);
        }
    }

    float z = 0.0f;
#pragma unroll
    for (int i = 0; i < SPT; ++i) {
        const float f = acc[i] + b2v;
        const float e = (f > 0.0f) ? f : (__expf(f) - 1.0f);  // elu(f)
        z = fmaf(e + 1.0f, s_ccw[s0 + i], z);
    }

    // combine the 4 node-slices of this output point
    z += __shfl_xor(z, 1);
    z += __shfl_xor(z, 2);
    if (chunk == 0) out[n] = z * xf * 0.5f;
}

extern "C" void kernel_launch(void* const* d_in, const int* in_sizes, int n_in,
                              void* d_out, int out_size, void* d_ws, size_t ws_size,
                              hipStream_t stream) {
    const float* x  = (const float*)d_in[0];
    const float* W1 = (const float*)d_in[1];
    const float* b1 = (const float*)d_in[2];
    const float* W2 = (const float*)d_in[3];
    const float* b2 = (const float*)d_in[4];
    float* out = (float*)d_out;

    const int N = in_sizes[0];              // 32768
    const int threads = 256;
    const int total   = N * 4;              // 4 threads per output point
    const int blocks  = (total + threads - 1) / threads;  // 512

    umnn_kernel<<<blocks, threads, 0, stream>>>(x, W1, b1, W2, b2, out, N);
}

// Round 2
// 69.379 us; speedup vs baseline: 1.2052x; 1.2052x over previous
//
#include <hip/hip_runtime.h>
#include <math.h>
#include <float.h>

#define NB 50      // NB_STEPS
#define NS 52      // 51 quadrature nodes padded to 52 (index 51: zero weight)
#define H  128     // hidden dim
#define SPT 13     // nodes per thread (4 threads/output * 13 = 52)

// Piecewise-linear reformulation:
//   f(X) = sum_h W2_h * relu(W1_h*X + b1_h) + b2  is continuous piecewise-linear
//   in X with breakpoints t_h = -b1_h/W1_h. Crossing t_h upward changes the
//   active set: +1 if W1_h>0 (unit turns on), -1 if W1_h<0 (unit turns off).
//   A(X) = A0 + prefix(dA over sorted t < X),  B(X) likewise;  f = A*X + B + b2.
// Each block redundantly builds sorted breakpoints + prefix arrays (~O(H) rank
// sort with LDS broadcast reads + wave shuffle scan), then evaluates each node
// with an 8-step branchless binary search instead of a 128-term dot product.
__global__ __launch_bounds__(256) void umnn_pw(
    const float* __restrict__ x,
    const float* __restrict__ W1,
    const float* __restrict__ b1,
    const float* __restrict__ W2,
    const float* __restrict__ b2,
    float* __restrict__ out,
    int N)
{
    __shared__ __align__(16) float s_tmp[H];   // unsorted breakpoints (for ranking)
    __shared__ float s_t[2 * H];               // sorted breakpoints + FLT_MAX pad
    __shared__ float s_dA[H], s_dB[H];         // sorted deltas
    __shared__ float s_pA[H + 1], s_pB[H + 1]; // prefix arrays, index k in [0,128]
    __shared__ float s_ccw[NS], s_ccs[NS];     // Clenshaw-Curtis weights/nodes
    __shared__ float s_red[8];                 // wave partials: base(A,B), scan totals

    const int tid = threadIdx.x;

    // ---- Phase 1: per-unit quantities (waves 0-1) | CC weights (wave 2) ----
    float t = 0.0f, dA = 0.0f, dB = 0.0f;
    if (tid < H) {
        const float w1 = W1[tid];
        const float bb = b1[tid];
        const float w2 = W2[tid];
        const bool zero = (w1 == 0.0f);
        t = zero ? FLT_MAX : (-bb / w1);
        const float sgn = (w1 > 0.0f) ? 1.0f : -1.0f;
        dA = zero ? 0.0f : sgn * w2 * w1;
        dB = zero ? 0.0f : sgn * w2 * bb;
        // contribution of the active set at X = -inf (units with W1<0),
        // plus constant relu(b1) for degenerate W1==0 units
        float baseA = (w1 < 0.0f) ? w2 * w1 : 0.0f;
        float baseB = (w1 < 0.0f) ? w2 * bb : (zero ? w2 * fmaxf(bb, 0.0f) : 0.0f);
        s_tmp[tid] = t;
        s_t[H + tid] = FLT_MAX;                // sentinel pad for binary search
#pragma unroll
        for (int off = 1; off < 64; off <<= 1) {
            baseA += __shfl_xor(baseA, off);
            baseB += __shfl_xor(baseB, off);
        }
        if ((tid & 63) == 0) {
            s_red[(tid >> 6) * 2 + 0] = baseA;
            s_red[(tid >> 6) * 2 + 1] = baseB;
        }
    } else if (tid < H + NS) {
        const int s = tid - H;
        if (s <= NB) {
            s_ccs[s] = __cosf((float)s * ((float)M_PI / (float)NB));
            float sum = 0.0f;
            for (int kk = 0; kk <= NB; kk += 2) {   // odd k: W[k]=0
                float L;
                if (s == 0)       L = 0.5f;                     // lam[:,0]=0.5
                else if (s == NB) L = 0.5f;                     // 0.5*cos(k*pi), k even
                else              L = __cosf((float)(kk * s) * ((float)M_PI / (float)NB));
                const float Wk = (kk == 0) ? 1.0f : 2.0f / (1.0f - (float)(kk * kk));
                sum += L * Wk;
            }
            s_ccw[s] = sum * (2.0f / (float)NB);
        } else {
            s_ccs[s] = 0.0f;   // padded node: finite position, zero weight
            s_ccw[s] = 0.0f;
        }
    }
    __syncthreads();

    // ---- Phase 2: rank (O(H) with broadcast LDS reads) and scatter ----
    if (tid < H) {
        const float4* t4 = (const float4*)s_tmp;
        int rank = 0;
#pragma unroll 8
        for (int j4 = 0; j4 < H / 4; ++j4) {
            const float4 v = t4[j4];   // wave-uniform address -> LDS broadcast
            const int jb = 4 * j4;
            rank += (v.x < t) || (v.x == t && (jb + 0) < tid);
            rank += (v.y < t) || (v.y == t && (jb + 1) < tid);
            rank += (v.z < t) || (v.z == t && (jb + 2) < tid);
            rank += (v.w < t) || (v.w == t && (jb + 3) < tid);
        }
        s_t[rank]  = t;    // tie-break by index makes rank a permutation
        s_dA[rank] = dA;
        s_dB[rank] = dB;
    }
    __syncthreads();

    // ---- Phase 3: inclusive shuffle-scan of sorted deltas -> prefix arrays ----
    float sa = 0.0f, sb = 0.0f;
    if (tid < H) {
        sa = s_dA[tid];
        sb = s_dB[tid];
        const int lane = tid & 63;
#pragma unroll
        for (int off = 1; off < 64; off <<= 1) {
            const float ta = __shfl_up(sa, off);
            const float tb = __shfl_up(sb, off);
            if (lane >= off) { sa += ta; sb += tb; }
        }
        if (lane == 63) {                       // wave totals for cross-wave fixup
            s_red[4 + (tid >> 6) * 2] = sa;
            s_red[5 + (tid >> 6) * 2] = sb;
        }
    }
    __syncthreads();
    if (tid < H) {
        const float A0 = s_red[0] + s_red[2];
        const float B0 = s_red[1] + s_red[3];
        const float addA = A0 + ((tid >= 64) ? s_red[4] : 0.0f);
        const float addB = B0 + ((tid >= 64) ? s_red[5] : 0.0f);
        s_pA[tid + 1] = sa + addA;
        s_pB[tid + 1] = sb + addB;
        if (tid == 0) { s_pA[0] = A0; s_pB[0] = B0; }
    }
    __syncthreads();

    // ---- Phase 4: evaluate quadrature nodes ----
    const int g = blockIdx.x * blockDim.x + tid;
    const int n = g >> 2;        // output point
    const int chunk = g & 3;     // which 13-node slice
    if (n >= N) return;

    const float xf  = x[n];
    const float b2v = b2[0];
    const int   s0  = chunk * SPT;

    float Xi[SPT];
    int   k[SPT];
#pragma unroll
    for (int i = 0; i < SPT; ++i) {
        Xi[i] = xf * (s_ccs[s0 + i] + 1.0f) * 0.5f;
        k[i]  = 0;
    }
    // Branchless lower-bound (count of t < Xi), 8 steps over 128 + FLT_MAX pad.
    // Step-outer / node-inner order: 13 independent LDS reads in flight per
    // step, hiding the ~120-cycle LDS latency of the dependent chain.
#pragma unroll
    for (int st = 128; st >= 1; st >>= 1) {
#pragma unroll
        for (int i = 0; i < SPT; ++i) {
            k[i] += (s_t[k[i] + st - 1] < Xi[i]) ? st : 0;
        }
    }
    float z = 0.0f;
#pragma unroll
    for (int i = 0; i < SPT; ++i) {
        const float A = s_pA[k[i]];
        const float B = s_pB[k[i]];
        const float f = fmaf(A, Xi[i], B) + b2v;
        const float e = (f > 0.0f) ? f : (__expf(f) - 1.0f);   // elu
        z = fmaf(e + 1.0f, s_ccw[s0 + i], z);
    }

    z += __shfl_xor(z, 1);
    z += __shfl_xor(z, 2);
    if (chunk == 0) out[n] = z * xf * 0.5f;
}

extern "C" void kernel_launch(void* const* d_in, const int* in_sizes, int n_in,
                              void* d_out, int out_size, void* d_ws, size_t ws_size,
                              hipStream_t stream) {
    const float* x  = (const float*)d_in[0];
    const float* W1 = (const float*)d_in[1];
    const float* b1 = (const float*)d_in[2];
    const float* W2 = (const float*)d_in[3];
    const float* b2 = (const float*)d_in[4];
    float* out = (float*)d_out;

    const int N = in_sizes[0];                  // 32768
    const int threads = 256;
    const int total = N * 4;                    // 4 threads per output point
    const int blocks = (total + threads - 1) / threads;   // 512

    umnn_pw<<<blocks, threads, 0, stream>>>(x, W1, b1, W2, b2, out, N);
}